// Round 14
// baseline (462.090 us; speedup 1.0000x reference)
//
#include <hip/hip_runtime.h>
#include <hip/hip_bf16.h>
#include <cstdint>
#include <cstddef>

#define PSP 110592          // 48*48*48 positions per batch
#define NCH 128
#define NB  2
#define CPW 68              // u32 stride of LCp rows (64 + 4 pad -> 2-way max)
#define TPB 4               // 64-pos tiles per GEMM block (864 blocks, round-8 best)
static constexpr float EPSV = 1e-5f;

typedef short bf16x8 __attribute__((ext_vector_type(8)));
typedef float f32x4  __attribute__((ext_vector_type(4)));

static __device__ __forceinline__ uint32_t pk2f(float lo, float hi) {
    __hip_bfloat162 h = __float22bfloat162_rn(make_float2(lo, hi));
    uint32_t u;
    __builtin_memcpy(&u, &h, 4);
    return u;
}
static __device__ __forceinline__ uint32_t pk2s(short lo, short hi) {
    return (uint32_t)(uint16_t)lo | ((uint32_t)(uint16_t)hi << 16);
}
static __device__ __forceinline__ float bf2float(short s) {
    uint32_t u = ((uint32_t)(uint16_t)s) << 16;
    return __builtin_bit_cast(float, u);
}
static __device__ __forceinline__ float bfLO(uint32_t w) {
    return __builtin_bit_cast(float, w << 16);
}
static __device__ __forceinline__ float bfHI(uint32_t w) {
    return __builtin_bit_cast(float, w & 0xffff0000u);
}
static __device__ __forceinline__ int swzb(int p) {
    return (((p & 7) ^ ((p >> 3) & 7)) << 4);
}

// ---------------------------------------------------------------------------
// tiny kernels
// ---------------------------------------------------------------------------
__global__ __launch_bounds__(256) void kv_kernel(
    const float* __restrict__ lang,
    const float* __restrict__ Wk, const float* __restrict__ bk,
    const float* __restrict__ Wv, const float* __restrict__ bv,
    float* __restrict__ kout, float* __restrict__ vout)
{
    int gid = blockIdx.x * 256 + threadIdx.x;     // 0..10239
    int sel = gid / 5120;
    int r   = gid % 5120;
    int b   = r / 2560;
    int o   = (r % 2560) / 20;
    int l   = r % 20;
    const float* W  = sel ? Wv : Wk;
    const float* bb = sel ? bv : bk;
    const float* lg = lang + b * 256 * 20 + l;
    float acc = bb[o];
    #pragma unroll 8
    for (int c = 0; c < 256; ++c)
        acc = fmaf(W[o * 256 + c], lg[c * 20], acc);
    (sel ? vout : kout)[b * 2560 + o * 20 + l] = acc;
}

__global__ __launch_bounds__(256) void wprep_kernel(
    const float* __restrict__ w0, const float* __restrict__ w1,
    const float* __restrict__ w2, const float* __restrict__ w3,
    const float* __restrict__ w4, const float* __restrict__ w5,
    short* __restrict__ wt)
{
    const int m = blockIdx.x >> 4, s = blockIdx.x & 15;
    const float* src = w0;
    if (m == 1) src = w1; else if (m == 2) src = w2; else if (m == 3) src = w3;
    else if (m == 4) src = w4; else if (m == 5) src = w5;
    short* dst = wt + m * NCH * NCH;
    const int i0 = s * 1024 + threadIdx.x * 4;
    f32x4 v = *(const f32x4*)(src + i0);
    *(uint2*)(dst + i0) = make_uint2(pk2f(v[0], v[1]), pk2f(v[2], v[3]));
}

__global__ __launch_bounds__(256) void knprep_kernel(
    const float* __restrict__ qs, const float* __restrict__ qs2,
    const float* __restrict__ kbuf,
    float* __restrict__ knb, float* __restrict__ cbb)
{
    __shared__ float mq[128], rqs[128], knl[2560];
    const int t = threadIdx.x, b = blockIdx.x;
    if (t < 128) {
        float m = qs[b * 128 + t] * (1.0f / PSP);
        float v = qs2[b * 128 + t] * (1.0f / PSP) - m * m;
        mq[t] = m;
        rqs[t] = rsqrtf(v + EPSV) * 0.25f;
    }
    __syncthreads();
    for (int e = t; e < 2560; e += 256) {
        int c = e / 20;
        float kv = rqs[c] * kbuf[b * 2560 + e];
        knl[e] = kv;
        knb[b * 2560 + e] = kv;
    }
    __syncthreads();
    if (t < 160) {
        int h = t / 20, l = t % 20;
        float s = 0.0f;
        #pragma unroll
        for (int i = 0; i < 16; ++i)
            s = fmaf(mq[h * 16 + i], knl[(h * 16 + i) * 20 + l], s);
        cbb[b * 160 + t] = s;
    }
}

// ---------------------------------------------------------------------------
// GEMM building blocks — STG layout: bf16 [64 p][128 c], byte = p*256 + c*2,
// XOR-swizzled by swzb(p). Thread u owns channels 4*(u>>3).. +3, pos (u&7)*8 +0..7.
// ---------------------------------------------------------------------------
struct PackW { uint32_t lo[8], hi[8]; };   // per j: lo=(c,c+1), hi=(c+2,c+3)

static __device__ __forceinline__ void ldpack_f32(const float* src, PackW& w) {
    const int t = threadIdx.x;
    const float* s = src + (size_t)(4 * (t >> 3)) * PSP + (t & 7) * 8;
    f32x4 r0a = *(const f32x4*)s,             r0b = *(const f32x4*)(s + 4);
    f32x4 r1a = *(const f32x4*)(s + PSP),     r1b = *(const f32x4*)(s + PSP + 4);
    f32x4 r2a = *(const f32x4*)(s + 2 * PSP), r2b = *(const f32x4*)(s + 2 * PSP + 4);
    f32x4 r3a = *(const f32x4*)(s + 3 * PSP), r3b = *(const f32x4*)(s + 3 * PSP + 4);
    #pragma unroll
    for (int j = 0; j < 4; ++j) {
        w.lo[j]     = pk2f(r0a[j], r1a[j]);
        w.lo[4 + j] = pk2f(r0b[j], r1b[j]);
        w.hi[j]     = pk2f(r2a[j], r3a[j]);
        w.hi[4 + j] = pk2f(r2b[j], r3b[j]);
    }
}
static __device__ __forceinline__ void ldpack_b16(const short* src, PackW& w) {
    const int t = threadIdx.x;
    const short* s = src + (size_t)(4 * (t >> 3)) * PSP + (t & 7) * 8;
    bf16x8 r0 = *(const bf16x8*)s;
    bf16x8 r1 = *(const bf16x8*)(s + PSP);
    bf16x8 r2 = *(const bf16x8*)(s + 2 * PSP);
    bf16x8 r3 = *(const bf16x8*)(s + 3 * PSP);
    #pragma unroll
    for (int j = 0; j < 8; ++j) { w.lo[j] = pk2s(r0[j], r1[j]); w.hi[j] = pk2s(r2[j], r3[j]); }
}
static __device__ __forceinline__ void ldpack_g4(const short* skip, const short* wgt,
        const float nm[4][NCH], PackW& w) {
    const int t = threadIdx.x;
    const int c = 4 * (t >> 3), p0 = (t & 7) * 8;
    const short* s = skip + (size_t)c * PSP + p0;
    const short* g = wgt  + (size_t)c * PSP + p0;
    bf16x8 s0 = *(const bf16x8*)s,             s1 = *(const bf16x8*)(s + PSP);
    bf16x8 s2 = *(const bf16x8*)(s + 2 * PSP), s3 = *(const bf16x8*)(s + 3 * PSP);
    bf16x8 g0 = *(const bf16x8*)g,             g1 = *(const bf16x8*)(g + PSP);
    bf16x8 g2 = *(const bf16x8*)(g + 2 * PSP), g3 = *(const bf16x8*)(g + 3 * PSP);
    float mA[4], rA[4], mB[4], rB[4];
    #pragma unroll
    for (int r = 0; r < 4; ++r) {
        mA[r] = nm[0][c + r]; rA[r] = nm[1][c + r];
        mB[r] = nm[2][c + r]; rB[r] = nm[3][c + r];
    }
    #pragma unroll
    for (int j = 0; j < 8; ++j) {
        float v0 = ((bf2float(s0[j]) - mA[0]) * rA[0]) * ((bf2float(g0[j]) - mB[0]) * rB[0]);
        float v1 = ((bf2float(s1[j]) - mA[1]) * rA[1]) * ((bf2float(g1[j]) - mB[1]) * rB[1]);
        float v2 = ((bf2float(s2[j]) - mA[2]) * rA[2]) * ((bf2float(g2[j]) - mB[2]) * rB[2]);
        float v3 = ((bf2float(s3[j]) - mA[3]) * rA[3]) * ((bf2float(g3[j]) - mB[3]) * rB[3]);
        w.lo[j] = pk2f(v0, v1);
        w.hi[j] = pk2f(v2, v3);
    }
}
static __device__ __forceinline__ void stage(char* STGb, const PackW& w) {
    const int t = threadIdx.x;
    const int c8 = (t >> 3) * 8, p0 = (t & 7) * 8;
    #pragma unroll
    for (int j = 0; j < 8; ++j) {
        int byte = (p0 + j) * 256 + c8;
        byte ^= ((j ^ (t & 7)) << 4);
        *(uint2*)(STGb + byte) = make_uint2(w.lo[j], w.hi[j]);
    }
}

static __device__ __forceinline__ void load_afrag16(const short* __restrict__ W16,
                                                    int wid, int lane, bf16x8 af[2][4]) {
    const int orow = wid * 32 + (lane & 15);
    const int cb   = (lane >> 4) * 8;
    #pragma unroll
    for (int mt = 0; mt < 2; ++mt)
        #pragma unroll
        for (int kt = 0; kt < 4; ++kt)
            af[mt][kt] = *(const bf16x8*)(W16 + (size_t)(orow + mt * 16) * NCH + kt * 32 + cb);
}

static __device__ __forceinline__ void run_mfmaX(const char* STGb, const bf16x8 af[2][4],
                                                 f32x4 acc[2][4], int lane) {
    const int l15 = lane & 15, kh = lane >> 4;
    #pragma unroll
    for (int nt = 0; nt < 4; ++nt) {
        const int p = nt * 16 + l15;
        const int sw = swzb(p);
        bf16x8 bf[4];
        #pragma unroll
        for (int kt = 0; kt < 4; ++kt)
            bf[kt] = *(const bf16x8*)(STGb + ((p * 256 + kt * 64 + kh * 16) ^ sw));
        #pragma unroll
        for (int kt = 0; kt < 4; ++kt) {
            acc[0][nt] = __builtin_amdgcn_mfma_f32_16x16x32_bf16(af[0][kt], bf[kt], acc[0][nt], 0, 0, 0);
            acc[1][nt] = __builtin_amdgcn_mfma_f32_16x16x32_bf16(af[1][kt], bf[kt], acc[1][nt], 0, 0, 0);
        }
    }
}
static __device__ __forceinline__ void zero_acc(f32x4 acc[2][4]) {
    #pragma unroll
    for (int m = 0; m < 2; ++m)
        #pragma unroll
        for (int n = 0; n < 4; ++n) acc[m][n] = (f32x4)0.0f;
}
// acc (+bias, relu) -> dest [p][c] bf16 swizzled tile
static __device__ __forceinline__ void acc_to_tile(char* dest, const f32x4 acc[2][4],
        const float bias[2][4], int wid, int lane) {
    const int l15 = lane & 15, og0 = wid * 32 + (lane >> 4) * 4;
    #pragma unroll
    for (int mt = 0; mt < 2; ++mt)
        #pragma unroll
        for (int nt = 0; nt < 4; ++nt) {
            const int o = og0 + mt * 16, p = nt * 16 + l15;
            const int sw = swzb(p);
            f32x4 a = acc[mt][nt];
            float z0 = fmaxf(a[0] + bias[mt][0], 0.0f);
            float z1 = fmaxf(a[1] + bias[mt][1], 0.0f);
            float z2 = fmaxf(a[2] + bias[mt][2], 0.0f);
            float z3 = fmaxf(a[3] + bias[mt][3], 0.0f);
            *(uint32_t*)(dest + ((p * 256 + o * 2) ^ sw))     = pk2f(z0, z1);
            *(uint32_t*)(dest + ((p * 256 + o * 2 + 4) ^ sw)) = pk2f(z2, z3);
        }
}
static __device__ __forceinline__ void write_LCp(uint32_t* LCp, const f32x4 acc[2][4],
                                                 int wid, int lane) {
    const int l15 = lane & 15, og = wid * 32 + (lane >> 4) * 4;
    #pragma unroll
    for (int mt = 0; mt < 2; ++mt)
        #pragma unroll
        for (int nt = 0; nt < 4; ++nt) {
            const int o2 = (og >> 1) + mt * 8, p = nt * 16 + l15;
            f32x4 a = acc[mt][nt];
            LCp[o2 * CPW + p]       = pk2f(a[0], a[1]);
            LCp[(o2 + 1) * CPW + p] = pk2f(a[2], a[3]);
        }
}
// epilogue: unpack LCp (uint4 reads), +bias (+relu), coalesced bf16 store;
// stats accumulated in caller registers.
template<bool RELU, bool STATS>
static __device__ __forceinline__ void epi2(const uint32_t* LCp, const float* __restrict__ bias,
        short* __restrict__ dst, float sS[4], float sQ[4])
{
    const int t = threadIdx.x;
    #pragma unroll
    for (int r = 0; r < 4; ++r) {
        const int u = r * 256 + t, o = u >> 3, ch = u & 7, hi = o & 1;
        const float bia = bias[o];
        const uint32_t* src = LCp + (o >> 1) * CPW + ch * 8;
        uint4 wa = *(const uint4*)src;
        uint4 wb = *(const uint4*)(src + 4);
        uint32_t ww[8] = {wa.x, wa.y, wa.z, wa.w, wb.x, wb.y, wb.z, wb.w};
        float v[8];
        #pragma unroll
        for (int j = 0; j < 8; ++j) v[j] = (hi ? bfHI(ww[j]) : bfLO(ww[j])) + bia;
        if (RELU) {
            #pragma unroll
            for (int j = 0; j < 8; ++j) v[j] = fmaxf(v[j], 0.0f);
        }
        *(uint4*)(dst + (size_t)o * PSP + ch * 8) =
            make_uint4(pk2f(v[0], v[1]), pk2f(v[2], v[3]),
                       pk2f(v[4], v[5]), pk2f(v[6], v[7]));
        if (STATS) {
            float s = 0.0f, q = 0.0f;
            #pragma unroll
            for (int j = 0; j < 8; ++j) { s += v[j]; q += v[j] * v[j]; }
            sS[r] += s; sQ[r] += q;
        }
    }
}
static __device__ __forceinline__ void flush_stats(const float sS[4], const float sQ[4],
        float* __restrict__ s_sum, float* __restrict__ s_sq)
{
    const int t = threadIdx.x;
    #pragma unroll
    for (int r = 0; r < 4; ++r) {
        float s = sS[r], q = sQ[r];
        s += __shfl_xor(s, 1); q += __shfl_xor(q, 1);
        s += __shfl_xor(s, 2); q += __shfl_xor(q, 2);
        s += __shfl_xor(s, 4); q += __shfl_xor(q, 4);
        if ((t & 7) == 0) {
            atomicAdd(&s_sum[r * 32 + (t >> 3)], s);
            atomicAdd(&s_sq [r * 32 + (t >> 3)], q);
        }
    }
}

// ---------------------------------------------------------------------------
// G12: q_pre = Wq*img (+stats) and skip_pre = Wpi*img (+stats); img read once.
// ---------------------------------------------------------------------------
__global__ __launch_bounds__(256) void g12_kernel(
    const float* __restrict__ img, const short* __restrict__ w16,
    const float* __restrict__ bq, const float* __restrict__ bpi,
    short* __restrict__ qout, short* __restrict__ sout,
    float* __restrict__ qs, float* __restrict__ qs2,
    float* __restrict__ ss, float* __restrict__ ss2)
{
    __shared__ __align__(16) char STGb[16384];
    __shared__ __align__(16) uint32_t LCp[64 * CPW];

    const int t = threadIdx.x, lane = t & 63, wid = t >> 6;
    const int b = blockIdx.y;
    const size_t bbase = (size_t)b * NCH * PSP;
    const int pbase = blockIdx.x * (64 * TPB);
    const int sb = b * NCH;

    bf16x8 afq[2][4], afp[2][4];
    load_afrag16(w16, wid, lane, afq);
    load_afrag16(w16 + NCH * NCH, wid, lane, afp);

    float qS[4] = {0, 0, 0, 0}, qQ[4] = {0, 0, 0, 0};
    float sS[4] = {0, 0, 0, 0}, sQ[4] = {0, 0, 0, 0};

    PackW w;
    ldpack_f32(img + bbase + pbase, w);

    for (int i = 0; i < TPB; ++i) {
        const int pblk = pbase + i * 64;
        stage(STGb, w);
        __syncthreads();                                    // A: STG ready
        if (i + 1 < TPB) ldpack_f32(img + bbase + pblk + 64, w);
        f32x4 acc[2][4];
        zero_acc(acc);
        run_mfmaX(STGb, afq, acc, lane);
        write_LCp(LCp, acc, wid, lane);
        __syncthreads();                                    // B: LCp(q) ready
        epi2<false, true>(LCp, bq, qout + bbase + pblk, qS, qQ);
        zero_acc(acc);
        run_mfmaX(STGb, afp, acc, lane);
        __syncthreads();                                    // C: LCp reads + STG reads done
        write_LCp(LCp, acc, wid, lane);
        __syncthreads();                                    // D: LCp(p) ready
        epi2<false, true>(LCp, bpi, sout + bbase + pblk, sS, sQ);
    }
    flush_stats(qS, qQ, qs + sb, qs2 + sb);
    flush_stats(sS, sQ, ss + sb, ss2 + sb);
}

// ---------------------------------------------------------------------------
// G3: weight_pre = Wpw * x (+stats)
// ---------------------------------------------------------------------------
__global__ __launch_bounds__(256) void g3_kernel(
    const short* __restrict__ x, const short* __restrict__ w16,
    const float* __restrict__ bpw, short* __restrict__ wout,
    float* __restrict__ wsu, float* __restrict__ ws2)
{
    __shared__ __align__(16) char STGb[16384];
    __shared__ __align__(16) uint32_t LCp[64 * CPW];

    const int t = threadIdx.x, lane = t & 63, wid = t >> 6;
    const int b = blockIdx.y;
    const size_t bbase = (size_t)b * NCH * PSP;
    const int pbase = blockIdx.x * (64 * TPB);
    const int sb = b * NCH;

    bf16x8 af[2][4];
    load_afrag16(w16, wid, lane, af);
    float wS[4] = {0, 0, 0, 0}, wQ[4] = {0, 0, 0, 0};

    PackW w;
    ldpack_b16(x + bbase + pbase, w);

    for (int i = 0; i < TPB; ++i) {
        const int pblk = pbase + i * 64;
        stage(STGb, w);
        __syncthreads();                                    // A
        if (i + 1 < TPB) ldpack_b16(x + bbase + pblk + 64, w);
        f32x4 acc[2][4];
        zero_acc(acc);
        run_mfmaX(STGb, af, acc, lane);
        write_LCp(LCp, acc, wid, lane);
        __syncthreads();                                    // B
        epi2<false, true>(LCp, bpw, wout + bbase + pblk, wS, wQ);
    }
    flush_stats(wS, wQ, wsu + sb, ws2 + sb);
}

// ---------------------------------------------------------------------------
// G456 (fused): out = relu(Wpo*(norm(skip)*norm(wgt)) + bpo)  [LDS only]
//               final = out * tanh(Wg2 * relu(Wg1*out + bg1) + bg2) -> f32
// ---------------------------------------------------------------------------
__global__ __launch_bounds__(256, 3) void g456_kernel(
    const short* __restrict__ skip, const short* __restrict__ wgt,
    const float* __restrict__ sA, const float* __restrict__ sA2,
    const float* __restrict__ sB, const float* __restrict__ sB2,
    const short* __restrict__ w16po, const float* __restrict__ bpo,
    const short* __restrict__ w16g1, const float* __restrict__ bg1,
    const short* __restrict__ w16g2, const float* __restrict__ bg2,
    float* __restrict__ fin)
{
    __shared__ __align__(16) char STGb[16384];          // g4 input tile
    __shared__ __align__(16) char OUTb[16384];          // 'out' tile [p][c] swz
    __shared__ __align__(16) char RTL[64 * CPW * 4];    // relu1 tile, then LCp
    __shared__ float nm[4][NCH];

    const int t = threadIdx.x, lane = t & 63, wid = t >> 6;
    const int b = blockIdx.y;
    const size_t bbase = (size_t)b * NCH * PSP;
    const int pbase = blockIdx.x * (64 * TPB);

    if (t < NCH) {
        float m = sA[b * NCH + t] * (1.0f / PSP);
        float v = sA2[b * NCH + t] * (1.0f / PSP) - m * m;
        nm[0][t] = m; nm[1][t] = rsqrtf(v + EPSV);
    } else {
        int c = t - NCH;
        float m = sB[b * NCH + c] * (1.0f / PSP);
        float v = sB2[b * NCH + c] * (1.0f / PSP) - m * m;
        nm[2][c] = m; nm[3][c] = rsqrtf(v + EPSV);
    }

    bf16x8 afPo[2][4], afG1[2][4], afG2[2][4];
    load_afrag16(w16po, wid, lane, afPo);
    load_afrag16(w16g1, wid, lane, afG1);
    load_afrag16(w16g2, wid, lane, afG2);

    const int og0 = wid * 32 + (lane >> 4) * 4;
    float bov[2][4], bg1v[2][4];
    #pragma unroll
    for (int mt = 0; mt < 2; ++mt)
        #pragma unroll
        for (int r = 0; r < 4; ++r) {
            bov[mt][r]  = bpo[og0 + mt * 16 + r];
            bg1v[mt][r] = bg1[og0 + mt * 16 + r];
        }
    __syncthreads();                 // nm ready

    PackW w;
    ldpack_g4(skip + bbase + pbase, wgt + bbase + pbase, nm, w);

    for (int i = 0; i < TPB; ++i) {
        const int pblk = pbase + i * 64;
        stage(STGb, w);
        __syncthreads();                                    // A: STG ready; prev OUT/LCp reads done
        if (i + 1 < TPB)
            ldpack_g4(skip + bbase + pblk + 64, wgt + bbase + pblk + 64, nm, w);
        f32x4 acc[2][4];
        zero_acc(acc);
        run_mfmaX(STGb, afPo, acc, lane);
        acc_to_tile(OUTb, acc, bov, wid, lane);             // out = relu(+bpo)
        __syncthreads();                                    // B: OUT ready
        zero_acc(acc);
        run_mfmaX(OUTb, afG1, acc, lane);
        acc_to_tile(RTL, acc, bg1v, wid, lane);             // relu1 = relu(+bg1)
        __syncthreads();                                    // C: RT ready
        zero_acc(acc);
        run_mfmaX(RTL, afG2, acc, lane);
        __syncthreads();                                    // D: RT reads done
        write_LCp((uint32_t*)RTL, acc, wid, lane);
        __syncthreads();                                    // E: LCp ready
        // final epilogue: f32 = out * tanh(LCp + bg2), coalesced c-major stores
        {
            const uint32_t* LCp = (const uint32_t*)RTL;
            float* dst = fin + bbase + pblk;
            #pragma unroll
            for (int r = 0; r < 4; ++r) {
                const int u = r * 256 + t, o2 = u >> 4, ch = u & 15;
                const float b0 = bg2[2 * o2], b1 = bg2[2 * o2 + 1];
                uint4 lc = *(const uint4*)(LCp + o2 * CPW + ch * 4);
                uint32_t lw[4] = {lc.x, lc.y, lc.z, lc.w};
                f32x4 oA, oB;
                #pragma unroll
                for (int j = 0; j < 4; ++j) {
                    const int p = ch * 4 + j;
                    uint32_t mw = *(const uint32_t*)(OUTb + ((p * 256 + o2 * 4) ^ swzb(p)));
                    oA[j] = bfLO(mw) * tanhf(bfLO(lw[j]) + b0);
                    oB[j] = bfHI(mw) * tanhf(bfHI(lw[j]) + b1);
                }
                *(f32x4*)(dst + (size_t)(2 * o2) * PSP + ch * 4)     = oA;
                *(f32x4*)(dst + (size_t)(2 * o2 + 1) * PSP + ch * 4) = oB;
            }
        }
        // no extra barrier: next iteration writes STGb only (disjoint); OUT/RT
        // rewritten only after the next A/B barriers.
    }
}

// ---------------------------------------------------------------------------
// Attention v3 (round-8 proven): 64 positions/block; kn/v/cb in LDS;
// q tile staged coalesced; X tile reuses q region; coalesced copyout.
// ---------------------------------------------------------------------------
__global__ __launch_bounds__(256) void attn3_kernel(
    const short* __restrict__ qpre, const float* __restrict__ knb,
    const float* __restrict__ cbb, const float* __restrict__ vbuf,
    short* __restrict__ xout)
{
    __shared__ __align__(16) uint32_t QX[64 * 65];   // q tile, then X tile
    __shared__ float KN[2560], VV[2560], CB[160];

    const int t = threadIdx.x;
    const int b = blockIdx.y;
    const int pblk = blockIdx.x * 64;
    const size_t bbase = (size_t)b * NCH * PSP;

    {
        const float* kn = knb + b * 2560;
        const float* vv = vbuf + b * 2560;
        #pragma unroll
        for (int e = t; e < 2560; e += 256) { KN[e] = kn[e]; VV[e] = vv[e]; }
        if (t < 160) CB[t] = cbb[b * 160 + t];
    }
    {
        const int c2 = t >> 2, p0 = (t & 3) * 16;
        const short* s0 = qpre + bbase + (size_t)(2 * c2) * PSP + pblk + p0;
        bf16x8 a0 = *(const bf16x8*)s0,         a1 = *(const bf16x8*)(s0 + 8);
        bf16x8 b0 = *(const bf16x8*)(s0 + PSP), b1 = *(const bf16x8*)(s0 + PSP + 8);
        uint32_t w[16];
        #pragma unroll
        for (int k = 0; k < 8; ++k) { w[k] = pk2s(a0[k], b0[k]); w[8 + k] = pk2s(a1[k], b1[k]); }
        uint32_t* base = QX + c2 * 65 + p0;
        #pragma unroll
        for (int k = 0; k < 8; ++k) *(uint2*)(base + 2 * k) = make_uint2(w[2 * k], w[2 * k + 1]);
    }
    __syncthreads();

    const int p = t & 63, h0 = t >> 6;
    uint32_t qw[16];
    #pragma unroll
    for (int i = 0; i < 8; ++i) {
        qw[i]     = QX[(h0 * 8 + i) * 65 + p];
        qw[8 + i] = QX[((h0 + 4) * 8 + i) * 65 + p];
    }
    __syncthreads();

    #pragma unroll 1
    for (int hh = 0; hh < 2; ++hh) {
        const int h = h0 + hh * 4;
        const int c0 = h * 16;
        float sim[20];
        #pragma unroll
        for (int l = 0; l < 20; ++l) sim[l] = -CB[h * 20 + l];
        #pragma unroll
        for (int i = 0; i < 8; ++i) {
            const uint32_t w = qw[hh * 8 + i];
            const float qlo = bfLO(w), qhi = bfHI(w);
            const float* k0 = KN + (c0 + 2 * i) * 20;
            #pragma unroll
            for (int l = 0; l < 20; ++l)
                sim[l] = fmaf(qlo, k0[l], fmaf(qhi, k0[20 + l], sim[l]));
        }
        float mx = sim[0];
        #pragma unroll
        for (int l = 1; l < 20; ++l) mx = fmaxf(mx, sim[l]);
        float se = 0.0f;
        #pragma unroll
        for (int l = 0; l < 20; ++l) { float e = __expf(sim[l] - mx); sim[l] = e; se += e; }
        const float inv = 1.0f / se;
        #pragma unroll
        for (int i = 0; i < 8; ++i) {
            const float* v0 = VV + (c0 + 2 * i) * 20;
            float x0 = 0.0f, x1 = 0.0f;
            #pragma unroll
            for (int l = 0; l < 20; ++l) {
                x0 = fmaf(sim[l], v0[l], x0);
                x1 = fmaf(sim[l], v0[20 + l], x1);
            }
            QX[p * 65 + h * 8 + i] = pk2f(x0 * inv, x1 * inv);
        }
    }
    __syncthreads();

    {
        const int lane = t & 63, w = t >> 6;
        uint32_t* gdst = (uint32_t*)(xout + bbase + (size_t)pblk * NCH);
        #pragma unroll
        for (int j = 0; j < 4; ++j) {
            const int pp = w * 4 + j * 16 + (lane >> 4);
            const int cw = (lane & 15) * 4;
            const uint32_t* s = QX + pp * 65 + cw;
            *(uint4*)(gdst + pp * 64 + cw) = make_uint4(s[0], s[1], s[2], s[3]);
        }
    }
}

// ---------------------------------------------------------------------------
extern "C" void kernel_launch(void* const* d_in, const int* in_sizes, int n_in,
                              void* d_out, int out_size, void* d_ws, size_t ws_size,
                              hipStream_t stream)
{
    const float* img  = (const float*)d_in[0];
    const float* lang = (const float*)d_in[1];
    const float* Wq   = (const float*)d_in[2];
    const float* bq   = (const float*)d_in[3];
    const float* Wk   = (const float*)d_in[4];
    const float* bk   = (const float*)d_in[5];
    const float* Wv   = (const float*)d_in[6];
    const float* bv   = (const float*)d_in[7];
    const float* Wpw  = (const float*)d_in[8];
    const float* bpw  = (const float*)d_in[9];
    const float* Wpi  = (const float*)d_in[10];
    const float* bpi  = (const float*)d_in[11];
    const float* Wpo  = (const float*)d_in[12];
    const float* bpo  = (const float*)d_in[13];
    const float* Wg1  = (const float*)d_in[14];
    const float* bg1  = (const float*)d_in[15];
    const float* Wg2  = (const float*)d_in[16];
    const float* bg2  = (const float*)d_in[17];
    float* outp = (float*)d_out;

    const size_t N = (size_t)NB * NCH * PSP;
    const size_t needed = 3 * N * sizeof(short) + 6 * NCH * NCH * sizeof(short)
                        + (3 * 2 * 2560 + 2 * 160 + 6 * 256) * sizeof(float);
    if (ws_size < needed) return;

    short* bufA = (short*)d_ws;          // q_pre, then weight_pre
    short* bufB = bufA + N;              // x
    short* bufC = bufB + N;              // skip_pre
    short* wt16 = bufC + N;
    float* kbuf = (float*)(wt16 + 6 * NCH * NCH);
    float* vbuf = kbuf + 2 * 2560;
    float* knb  = vbuf + 2 * 2560;
    float* cbb  = knb + 2 * 2560;
    float* st   = cbb + 2 * 160;
    float* qs   = st;
    float* qs2  = st + 256;
    float* ss   = st + 512;
    float* ss2  = st + 768;
    float* wsu  = st + 1024;
    float* ws2  = st + 1280;

    (void)hipMemsetAsync(st, 0, 6 * 256 * sizeof(float), stream);
    kv_kernel<<<dim3(40), dim3(256), 0, stream>>>(lang, Wk, bk, Wv, bv, kbuf, vbuf);
    wprep_kernel<<<dim3(96), dim3(256), 0, stream>>>(Wq, Wpi, Wpw, Wpo, Wg1, Wg2, wt16);

    const dim3 gg(PSP / (64 * TPB), NB), gb(256);

    g12_kernel<<<gg, gb, 0, stream>>>(img, wt16, bq, bpi, bufA, bufC, qs, qs2, ss, ss2);
    knprep_kernel<<<dim3(NB), dim3(256), 0, stream>>>(qs, qs2, kbuf, knb, cbb);
    attn3_kernel<<<dim3(PSP / 64, NB), gb, 0, stream>>>(bufA, knb, cbb, vbuf, bufB);
    g3_kernel<<<gg, gb, 0, stream>>>(bufB, wt16 + 2 * NCH * NCH, bpw, bufA, wsu, ws2);
    g456_kernel<<<gg, gb, 0, stream>>>(bufC, bufA, ss, ss2, wsu, ws2,
                                       wt16 + 3 * NCH * NCH, bpo,
                                       wt16 + 4 * NCH * NCH, bg1,
                                       wt16 + 5 * NCH * NCH, bg2, outp);
}

// Round 15
// 321.741 us; speedup vs baseline: 1.4362x; 1.4362x over previous
//
#include <hip/hip_runtime.h>
#include <cstdint>
#include <cstddef>

#define PSP 110592          // 48*48*48 positions per batch
#define NCH 128
#define NB  2
#define CPW 68              // u32 stride of LCp rows (64 + 4 pad -> 2-way max)
#define TPB 4               // 64-pos tiles per GEMM block
static constexpr float EPSV = 1e-5f;

typedef short bf16x8 __attribute__((ext_vector_type(8)));
typedef float f32x4  __attribute__((ext_vector_type(4)));

static __device__ __forceinline__ short f2bf(float f) {
    uint32_t u = __builtin_bit_cast(uint32_t, f);
    u += 0x7FFF + ((u >> 16) & 1);          // RNE
    return (short)(u >> 16);
}
static __device__ __forceinline__ float bf2float(short s) {
    uint32_t u = ((uint32_t)(uint16_t)s) << 16;
    return __builtin_bit_cast(float, u);
}
static __device__ __forceinline__ float bfLO(uint32_t w) {
    return __builtin_bit_cast(float, w << 16);
}
static __device__ __forceinline__ float bfHI(uint32_t w) {
    return __builtin_bit_cast(float, w & 0xffff0000u);
}
static __device__ __forceinline__ uint32_t pk2f(float lo, float hi) {
    return (uint32_t)(uint16_t)f2bf(lo) | ((uint32_t)(uint16_t)f2bf(hi) << 16);
}
static __device__ __forceinline__ uint32_t pk2s(short lo, short hi) {
    return (uint32_t)(uint16_t)lo | ((uint32_t)(uint16_t)hi << 16);
}
static __device__ __forceinline__ int swzb(int p) {
    return (((p & 7) ^ ((p >> 3) & 7)) << 4);
}

// ---------------------------------------------------------------------------
// tiny kernels
// ---------------------------------------------------------------------------
__global__ __launch_bounds__(256) void kv_kernel(
    const float* __restrict__ lang,
    const float* __restrict__ Wk, const float* __restrict__ bk,
    const float* __restrict__ Wv, const float* __restrict__ bv,
    float* __restrict__ kout, float* __restrict__ vout)
{
    int gid = blockIdx.x * 256 + threadIdx.x;     // 0..10239
    int sel = gid / 5120;
    int r   = gid % 5120;
    int b   = r / 2560;
    int o   = (r % 2560) / 20;
    int l   = r % 20;
    const float* W  = sel ? Wv : Wk;
    const float* bb = sel ? bv : bk;
    const float* lg = lang + b * 256 * 20 + l;
    float acc = bb[o];
    #pragma unroll 8
    for (int c = 0; c < 256; ++c)
        acc = fmaf(W[o * 256 + c], lg[c * 20], acc);
    (sel ? vout : kout)[b * 2560 + o * 20 + l] = acc;
}

__global__ __launch_bounds__(256) void wprep_kernel(
    const float* __restrict__ w0, const float* __restrict__ w1,
    const float* __restrict__ w2, const float* __restrict__ w3,
    const float* __restrict__ w4, const float* __restrict__ w5,
    short* __restrict__ wt)
{
    const int m = blockIdx.x >> 4, s = blockIdx.x & 15;
    const float* src = w0;
    if (m == 1) src = w1; else if (m == 2) src = w2; else if (m == 3) src = w3;
    else if (m == 4) src = w4; else if (m == 5) src = w5;
    short* dst = wt + m * NCH * NCH;
    const int i0 = s * 1024 + threadIdx.x * 4;
    f32x4 v = *(const f32x4*)(src + i0);
    *(uint2*)(dst + i0) = make_uint2(pk2f(v[0], v[1]), pk2f(v[2], v[3]));
}

__global__ __launch_bounds__(256) void knprep_kernel(
    const float* __restrict__ qs, const float* __restrict__ qs2,
    const float* __restrict__ kbuf,
    float* __restrict__ knb, float* __restrict__ cbb)
{
    __shared__ float mq[128], rqs[128], knl[2560];
    const int t = threadIdx.x, b = blockIdx.x;
    if (t < 128) {
        float m = qs[b * 128 + t] * (1.0f / PSP);
        float v = qs2[b * 128 + t] * (1.0f / PSP) - m * m;
        mq[t] = m;
        rqs[t] = rsqrtf(v + EPSV) * 0.25f;
    }
    __syncthreads();
    for (int e = t; e < 2560; e += 256) {
        int c = e / 20;
        float kv = rqs[c] * kbuf[b * 2560 + e];
        knl[e] = kv;
        knb[b * 2560 + e] = kv;
    }
    __syncthreads();
    if (t < 160) {
        int h = t / 20, l = t % 20;
        float s = 0.0f;
        #pragma unroll
        for (int i = 0; i < 16; ++i)
            s = fmaf(mq[h * 16 + i], knl[(h * 16 + i) * 20 + l], s);
        cbb[b * 160 + t] = s;
    }
}

// ---------------------------------------------------------------------------
// GEMM building blocks — STG layout: bf16 [64 p][128 c], byte = p*256 + c*2,
// XOR-swizzled by swzb(p). Thread u owns channels 4*(u>>3).. +3, pos (u&7)*8 +0..7.
// ---------------------------------------------------------------------------
struct PackW { uint32_t lo[8], hi[8]; };   // per j: lo=(c,c+1), hi=(c+2,c+3)

static __device__ __forceinline__ void ldpack_f32(const float* src, PackW& w) {
    const int t = threadIdx.x;
    const float* s = src + (size_t)(4 * (t >> 3)) * PSP + (t & 7) * 8;
    f32x4 r0a = *(const f32x4*)s,             r0b = *(const f32x4*)(s + 4);
    f32x4 r1a = *(const f32x4*)(s + PSP),     r1b = *(const f32x4*)(s + PSP + 4);
    f32x4 r2a = *(const f32x4*)(s + 2 * PSP), r2b = *(const f32x4*)(s + 2 * PSP + 4);
    f32x4 r3a = *(const f32x4*)(s + 3 * PSP), r3b = *(const f32x4*)(s + 3 * PSP + 4);
    #pragma unroll
    for (int j = 0; j < 4; ++j) {
        w.lo[j]     = pk2f(r0a[j], r1a[j]);
        w.lo[4 + j] = pk2f(r0b[j], r1b[j]);
        w.hi[j]     = pk2f(r2a[j], r3a[j]);
        w.hi[4 + j] = pk2f(r2b[j], r3b[j]);
    }
}
static __device__ __forceinline__ void ldpack_b16(const short* src, PackW& w) {
    const int t = threadIdx.x;
    const short* s = src + (size_t)(4 * (t >> 3)) * PSP + (t & 7) * 8;
    bf16x8 r0 = *(const bf16x8*)s;
    bf16x8 r1 = *(const bf16x8*)(s + PSP);
    bf16x8 r2 = *(const bf16x8*)(s + 2 * PSP);
    bf16x8 r3 = *(const bf16x8*)(s + 3 * PSP);
    #pragma unroll
    for (int j = 0; j < 8; ++j) { w.lo[j] = pk2s(r0[j], r1[j]); w.hi[j] = pk2s(r2[j], r3[j]); }
}
static __device__ __forceinline__ void ldpack_g4(const short* skip, const short* wgt,
        const float nm[4][NCH], PackW& w) {
    const int t = threadIdx.x;
    const int c = 4 * (t >> 3), p0 = (t & 7) * 8;
    const short* s = skip + (size_t)c * PSP + p0;
    const short* g = wgt  + (size_t)c * PSP + p0;
    bf16x8 s0 = *(const bf16x8*)s,             s1 = *(const bf16x8*)(s + PSP);
    bf16x8 s2 = *(const bf16x8*)(s + 2 * PSP), s3 = *(const bf16x8*)(s + 3 * PSP);
    bf16x8 g0 = *(const bf16x8*)g,             g1 = *(const bf16x8*)(g + PSP);
    bf16x8 g2 = *(const bf16x8*)(g + 2 * PSP), g3 = *(const bf16x8*)(g + 3 * PSP);
    float mA[4], rA[4], mB[4], rB[4];
    #pragma unroll
    for (int r = 0; r < 4; ++r) {
        mA[r] = nm[0][c + r]; rA[r] = nm[1][c + r];
        mB[r] = nm[2][c + r]; rB[r] = nm[3][c + r];
    }
    #pragma unroll
    for (int j = 0; j < 8; ++j) {
        float v0 = ((bf2float(s0[j]) - mA[0]) * rA[0]) * ((bf2float(g0[j]) - mB[0]) * rB[0]);
        float v1 = ((bf2float(s1[j]) - mA[1]) * rA[1]) * ((bf2float(g1[j]) - mB[1]) * rB[1]);
        float v2 = ((bf2float(s2[j]) - mA[2]) * rA[2]) * ((bf2float(g2[j]) - mB[2]) * rB[2]);
        float v3 = ((bf2float(s3[j]) - mA[3]) * rA[3]) * ((bf2float(g3[j]) - mB[3]) * rB[3]);
        w.lo[j] = pk2f(v0, v1);
        w.hi[j] = pk2f(v2, v3);
    }
}
static __device__ __forceinline__ void stage(char* STGb, const PackW& w) {
    const int t = threadIdx.x;
    const int c8 = (t >> 3) * 8, p0 = (t & 7) * 8;
    #pragma unroll
    for (int j = 0; j < 8; ++j) {
        int byte = (p0 + j) * 256 + c8;
        byte ^= ((j ^ (t & 7)) << 4);
        *(uint2*)(STGb + byte) = make_uint2(w.lo[j], w.hi[j]);
    }
}

static __device__ __forceinline__ void load_afrag16(const short* __restrict__ W16,
                                                    int wid, int lane, bf16x8 af[2][4]) {
    const int orow = wid * 32 + (lane & 15);
    const int cb   = (lane >> 4) * 8;
    #pragma unroll
    for (int mt = 0; mt < 2; ++mt)
        #pragma unroll
        for (int kt = 0; kt < 4; ++kt)
            af[mt][kt] = *(const bf16x8*)(W16 + (size_t)(orow + mt * 16) * NCH + kt * 32 + cb);
}

static __device__ __forceinline__ void run_mfmaX(const char* STGb, const bf16x8 af[2][4],
                                                 f32x4 acc[2][4], int lane) {
    const int l15 = lane & 15, kh = lane >> 4;
    #pragma unroll
    for (int nt = 0; nt < 4; ++nt) {
        const int p = nt * 16 + l15;
        const int sw = swzb(p);
        bf16x8 bf[4];
        #pragma unroll
        for (int kt = 0; kt < 4; ++kt)
            bf[kt] = *(const bf16x8*)(STGb + ((p * 256 + kt * 64 + kh * 16) ^ sw));
        #pragma unroll
        for (int kt = 0; kt < 4; ++kt) {
            acc[0][nt] = __builtin_amdgcn_mfma_f32_16x16x32_bf16(af[0][kt], bf[kt], acc[0][nt], 0, 0, 0);
            acc[1][nt] = __builtin_amdgcn_mfma_f32_16x16x32_bf16(af[1][kt], bf[kt], acc[1][nt], 0, 0, 0);
        }
    }
}
static __device__ __forceinline__ void zero_acc(f32x4 acc[2][4]) {
    #pragma unroll
    for (int m = 0; m < 2; ++m)
        #pragma unroll
        for (int n = 0; n < 4; ++n) acc[m][n] = (f32x4)0.0f;
}
static __device__ __forceinline__ void write_LCp(uint32_t* LCp, const f32x4 acc[2][4],
                                                 int wid, int lane) {
    const int l15 = lane & 15, og = wid * 32 + (lane >> 4) * 4;
    #pragma unroll
    for (int mt = 0; mt < 2; ++mt)
        #pragma unroll
        for (int nt = 0; nt < 4; ++nt) {
            const int o2 = (og >> 1) + mt * 8, p = nt * 16 + l15;
            f32x4 a = acc[mt][nt];
            LCp[o2 * CPW + p]       = pk2f(a[0], a[1]);
            LCp[(o2 + 1) * CPW + p] = pk2f(a[2], a[3]);
        }
}
// epilogue: unpack LCp (uint4 conflict-free reads), +bias (+relu), coalesced
// bf16 store; stats accumulated in caller registers.
template<bool RELU, bool STATS>
static __device__ __forceinline__ void epi2(const uint32_t* LCp, const float* __restrict__ bias,
        short* __restrict__ dst, float sS[4], float sQ[4])
{
    const int t = threadIdx.x;
    #pragma unroll
    for (int r = 0; r < 4; ++r) {
        const int u = r * 256 + t, o = u >> 3, ch = u & 7, hi = o & 1;
        const float bia = bias[o];
        const uint32_t* src = LCp + (o >> 1) * CPW + ch * 8;
        uint4 wa = *(const uint4*)src;
        uint4 wb = *(const uint4*)(src + 4);
        uint32_t ww[8] = {wa.x, wa.y, wa.z, wa.w, wb.x, wb.y, wb.z, wb.w};
        float v[8];
        #pragma unroll
        for (int j = 0; j < 8; ++j) v[j] = (hi ? bfHI(ww[j]) : bfLO(ww[j])) + bia;
        if (RELU) {
            #pragma unroll
            for (int j = 0; j < 8; ++j) v[j] = fmaxf(v[j], 0.0f);
        }
        bf16x8 s8;
        #pragma unroll
        for (int j = 0; j < 8; ++j) s8[j] = f2bf(v[j]);
        *(bf16x8*)(dst + (size_t)o * PSP + ch * 8) = s8;
        if (STATS) {
            float s = 0.0f, q = 0.0f;
            #pragma unroll
            for (int j = 0; j < 8; ++j) { s += v[j]; q += v[j] * v[j]; }
            sS[r] += s; sQ[r] += q;
        }
    }
}
static __device__ __forceinline__ void flush_stats(const float sS[4], const float sQ[4],
        float* __restrict__ s_sum, float* __restrict__ s_sq)
{
    const int t = threadIdx.x;
    #pragma unroll
    for (int r = 0; r < 4; ++r) {
        float s = sS[r], q = sQ[r];
        s += __shfl_xor(s, 1); q += __shfl_xor(q, 1);
        s += __shfl_xor(s, 2); q += __shfl_xor(q, 2);
        s += __shfl_xor(s, 4); q += __shfl_xor(q, 4);
        if ((t & 7) == 0) {
            atomicAdd(&s_sum[r * 32 + (t >> 3)], s);
            atomicAdd(&s_sq [r * 32 + (t >> 3)], q);
        }
    }
}

// ---------------------------------------------------------------------------
// G12: q_pre = Wq*img (+stats) and skip_pre = Wpi*img (+stats); img read once.
// ---------------------------------------------------------------------------
__global__ __launch_bounds__(256) void g12_kernel(
    const float* __restrict__ img, const short* __restrict__ w16,
    const float* __restrict__ bq, const float* __restrict__ bpi,
    short* __restrict__ qout, short* __restrict__ sout,
    float* __restrict__ qs, float* __restrict__ qs2,
    float* __restrict__ ss, float* __restrict__ ss2)
{
    __shared__ __align__(16) char STGb[16384];
    __shared__ __align__(16) uint32_t LCp[64 * CPW];

    const int t = threadIdx.x, lane = t & 63, wid = t >> 6;
    const int b = blockIdx.y;
    const size_t bbase = (size_t)b * NCH * PSP;
    const int pbase = blockIdx.x * (64 * TPB);
    const int sb = b * NCH;

    bf16x8 afq[2][4], afp[2][4];
    load_afrag16(w16, wid, lane, afq);
    load_afrag16(w16 + NCH * NCH, wid, lane, afp);

    float qS[4] = {0, 0, 0, 0}, qQ[4] = {0, 0, 0, 0};
    float sS[4] = {0, 0, 0, 0}, sQ[4] = {0, 0, 0, 0};

    PackW w;
    ldpack_f32(img + bbase + pbase, w);

    for (int i = 0; i < TPB; ++i) {
        const int pblk = pbase + i * 64;
        stage(STGb, w);
        __syncthreads();                                    // A: STG ready
        if (i + 1 < TPB) ldpack_f32(img + bbase + pblk + 64, w);
        f32x4 acc[2][4];
        zero_acc(acc);
        run_mfmaX(STGb, afq, acc, lane);
        write_LCp(LCp, acc, wid, lane);
        __syncthreads();                                    // B: LCp(q) ready
        epi2<false, true>(LCp, bq, qout + bbase + pblk, qS, qQ);
        zero_acc(acc);
        run_mfmaX(STGb, afp, acc, lane);
        __syncthreads();                                    // C: LCp reads + STG reads done
        write_LCp(LCp, acc, wid, lane);
        __syncthreads();                                    // D: LCp(p) ready
        epi2<false, true>(LCp, bpi, sout + bbase + pblk, sS, sQ);
    }
    flush_stats(qS, qQ, qs + sb, qs2 + sb);
    flush_stats(sS, sQ, ss + sb, ss2 + sb);
}

// ---------------------------------------------------------------------------
// G3: weight_pre = Wpw * x (+stats)
// ---------------------------------------------------------------------------
__global__ __launch_bounds__(256) void g3_kernel(
    const short* __restrict__ x, const short* __restrict__ w16,
    const float* __restrict__ bpw, short* __restrict__ wout,
    float* __restrict__ wsu, float* __restrict__ ws2)
{
    __shared__ __align__(16) char STGb[16384];
    __shared__ __align__(16) uint32_t LCp[64 * CPW];

    const int t = threadIdx.x, lane = t & 63, wid = t >> 6;
    const int b = blockIdx.y;
    const size_t bbase = (size_t)b * NCH * PSP;
    const int pbase = blockIdx.x * (64 * TPB);
    const int sb = b * NCH;

    bf16x8 af[2][4];
    load_afrag16(w16, wid, lane, af);
    float wS[4] = {0, 0, 0, 0}, wQ[4] = {0, 0, 0, 0};

    PackW w;
    ldpack_b16(x + bbase + pbase, w);

    for (int i = 0; i < TPB; ++i) {
        const int pblk = pbase + i * 64;
        stage(STGb, w);
        __syncthreads();                                    // A
        if (i + 1 < TPB) ldpack_b16(x + bbase + pblk + 64, w);
        f32x4 acc[2][4];
        zero_acc(acc);
        run_mfmaX(STGb, af, acc, lane);
        write_LCp(LCp, acc, wid, lane);
        __syncthreads();                                    // B
        epi2<false, true>(LCp, bpw, wout + bbase + pblk, wS, wQ);
    }
    flush_stats(wS, wQ, wsu + sb, ws2 + sb);
}

// ---------------------------------------------------------------------------
// G4: out = relu(Wpo * (norm(skip)*norm(weight)))
// ---------------------------------------------------------------------------
__global__ __launch_bounds__(256) void g4_kernel(
    const short* __restrict__ skip, const short* __restrict__ wgt,
    const float* __restrict__ sA, const float* __restrict__ sA2,
    const float* __restrict__ sB, const float* __restrict__ sB2,
    const short* __restrict__ w16, const float* __restrict__ bpo,
    short* __restrict__ outp)
{
    __shared__ __align__(16) char STGb[16384];
    __shared__ __align__(16) uint32_t LCp[64 * CPW];
    __shared__ float nm[4][NCH];

    const int t = threadIdx.x, lane = t & 63, wid = t >> 6;
    const int b = blockIdx.y;
    const size_t bbase = (size_t)b * NCH * PSP;
    const int pbase = blockIdx.x * (64 * TPB);

    if (t < NCH) {
        float m = sA[b * NCH + t] * (1.0f / PSP);
        float v = sA2[b * NCH + t] * (1.0f / PSP) - m * m;
        nm[0][t] = m; nm[1][t] = rsqrtf(v + EPSV);
    } else {
        int c = t - NCH;
        float m = sB[b * NCH + c] * (1.0f / PSP);
        float v = sB2[b * NCH + c] * (1.0f / PSP) - m * m;
        nm[2][c] = m; nm[3][c] = rsqrtf(v + EPSV);
    }
    bf16x8 af[2][4];
    load_afrag16(w16, wid, lane, af);
    __syncthreads();                 // nm ready

    PackW w;
    ldpack_g4(skip + bbase + pbase, wgt + bbase + pbase, nm, w);
    float dS[4], dQ[4];              // unused (no stats)

    for (int i = 0; i < TPB; ++i) {
        const int pblk = pbase + i * 64;
        stage(STGb, w);
        __syncthreads();                                    // A
        if (i + 1 < TPB)
            ldpack_g4(skip + bbase + pblk + 64, wgt + bbase + pblk + 64, nm, w);
        f32x4 acc[2][4];
        zero_acc(acc);
        run_mfmaX(STGb, af, acc, lane);
        write_LCp(LCp, acc, wid, lane);
        __syncthreads();                                    // B
        epi2<true, false>(LCp, bpo, outp + bbase + pblk, dS, dQ);
    }
}

// ---------------------------------------------------------------------------
// G56: final = out * tanh(Wg2 * relu(Wg1*out + bg1) + bg2)
// RTL region holds relu1 tile ([p][c] swz, 16KB) then LCp (17.4KB).
// ---------------------------------------------------------------------------
__global__ __launch_bounds__(256) void g56_kernel(
    const short* __restrict__ outb, const short* __restrict__ w16g1,
    const float* __restrict__ bg1, const short* __restrict__ w16g2,
    const float* __restrict__ bg2, float* __restrict__ fin)
{
    __shared__ __align__(16) char STGb[16384];
    __shared__ __align__(16) char RTL[64 * CPW * 4];   // relu1 [p][c], then LCp

    const int t = threadIdx.x, lane = t & 63, wid = t >> 6;
    const int b = blockIdx.y;
    const size_t bbase = (size_t)b * NCH * PSP;
    const int pbase = blockIdx.x * (64 * TPB);

    bf16x8 af1[2][4], af2[2][4];
    load_afrag16(w16g1, wid, lane, af1);
    load_afrag16(w16g2, wid, lane, af2);

    float bg1v[2][4];
    {
        const int og = wid * 32 + (lane >> 4) * 4;
        #pragma unroll
        for (int mt = 0; mt < 2; ++mt)
            #pragma unroll
            for (int r = 0; r < 4; ++r) bg1v[mt][r] = bg1[og + mt * 16 + r];
    }

    PackW w;
    ldpack_b16(outb + bbase + pbase, w);

    for (int i = 0; i < TPB; ++i) {
        const int pblk = pbase + i * 64;
        stage(STGb, w);
        __syncthreads();                                    // A: STG ready
        if (i + 1 < TPB) ldpack_b16(outb + bbase + pblk + 64, w);
        f32x4 acc[2][4];
        zero_acc(acc);
        run_mfmaX(STGb, af1, acc, lane);
        // relu1 -> RTL as [p][c] swizzled bf16
        {
            const int l15 = lane & 15, og = wid * 32 + (lane >> 4) * 4;
            #pragma unroll
            for (int mt = 0; mt < 2; ++mt)
                #pragma unroll
                for (int nt = 0; nt < 4; ++nt) {
                    const int o = og + mt * 16, p = nt * 16 + l15;
                    const int sw = swzb(p);
                    f32x4 a = acc[mt][nt];
                    float z0 = fmaxf(a[0] + bg1v[mt][0], 0.0f);
                    float z1 = fmaxf(a[1] + bg1v[mt][1], 0.0f);
                    float z2 = fmaxf(a[2] + bg1v[mt][2], 0.0f);
                    float z3 = fmaxf(a[3] + bg1v[mt][3], 0.0f);
                    *(uint32_t*)(RTL + ((p * 256 + o * 2) ^ sw))     = pk2f(z0, z1);
                    *(uint32_t*)(RTL + ((p * 256 + o * 2 + 4) ^ sw)) = pk2f(z2, z3);
                }
        }
        __syncthreads();                                    // B: RT ready
        zero_acc(acc);
        run_mfmaX(RTL, af2, acc, lane);
        __syncthreads();                                    // C: RT reads done
        write_LCp((uint32_t*)RTL, acc, wid, lane);
        __syncthreads();                                    // D: LCp ready
        // final epilogue: f32 = out * tanh(LCp + bg2)
        {
            const uint32_t* LCp = (const uint32_t*)RTL;
            float* dst = fin + bbase + pblk;
            #pragma unroll
            for (int r = 0; r < 4; ++r) {
                const int u = r * 256 + t, o2 = u >> 4, ch = u & 15;
                const float b0 = bg2[2 * o2], b1 = bg2[2 * o2 + 1];
                uint4 lc = *(const uint4*)(LCp + o2 * CPW + ch * 4);
                uint32_t lw[4] = {lc.x, lc.y, lc.z, lc.w};
                f32x4 oA, oB;
                #pragma unroll
                for (int j = 0; j < 4; ++j) {
                    const int p = ch * 4 + j;
                    uint32_t mw = *(const uint32_t*)(STGb + ((p * 256 + o2 * 4) ^ swzb(p)));
                    oA[j] = bfLO(mw) * tanhf(bfLO(lw[j]) + b0);
                    oB[j] = bfHI(mw) * tanhf(bfHI(lw[j]) + b1);
                }
                *(f32x4*)(dst + (size_t)(2 * o2) * PSP + ch * 4)     = oA;
                *(f32x4*)(dst + (size_t)(2 * o2 + 1) * PSP + ch * 4) = oB;
            }
        }
        __syncthreads();                                    // E: STG/LCp reads done
    }
}

// ---------------------------------------------------------------------------
// Attention v3 (round-8 proven): 64 positions/block; kn/v/cb in LDS;
// q tile staged coalesced; X tile reuses q region; coalesced copyout.
// ---------------------------------------------------------------------------
__global__ __launch_bounds__(256) void attn3_kernel(
    const short* __restrict__ qpre, const float* __restrict__ knb,
    const float* __restrict__ cbb, const float* __restrict__ vbuf,
    short* __restrict__ xout)
{
    __shared__ __align__(16) uint32_t QX[64 * 65];   // q tile, then X tile
    __shared__ float KN[2560], VV[2560], CB[160];

    const int t = threadIdx.x;
    const int b = blockIdx.y;
    const int pblk = blockIdx.x * 64;
    const size_t bbase = (size_t)b * NCH * PSP;

    {
        const float* kn = knb + b * 2560;
        const float* vv = vbuf + b * 2560;
        #pragma unroll
        for (int e = t; e < 2560; e += 256) { KN[e] = kn[e]; VV[e] = vv[e]; }
        if (t < 160) CB[t] = cbb[b * 160 + t];
    }
    {
        const int c2 = t >> 2, p0 = (t & 3) * 16;
        const short* s0 = qpre + bbase + (size_t)(2 * c2) * PSP + pblk + p0;
        bf16x8 a0 = *(const bf16x8*)s0,         a1 = *(const bf16x8*)(s0 + 8);
        bf16x8 b0 = *(const bf16x8*)(s0 + PSP), b1 = *(const bf16x8*)(s0 + PSP + 8);
        uint32_t w[16];
        #pragma unroll
        for (int k = 0; k < 8; ++k) { w[k] = pk2s(a0[k], b0[k]); w[8 + k] = pk2s(a1[k], b1[k]); }
        uint32_t* base = QX + c2 * 65 + p0;
        #pragma unroll
        for (int k = 0; k < 8; ++k) *(uint2*)(base + 2 * k) = make_uint2(w[2 * k], w[2 * k + 1]);
    }
    __syncthreads();

    const int p = t & 63, h0 = t >> 6;
    uint32_t qw[16];
    #pragma unroll
    for (int i = 0; i < 8; ++i) {
        qw[i]     = QX[(h0 * 8 + i) * 65 + p];
        qw[8 + i] = QX[((h0 + 4) * 8 + i) * 65 + p];
    }
    __syncthreads();

    #pragma unroll 1
    for (int hh = 0; hh < 2; ++hh) {
        const int h = h0 + hh * 4;
        const int c0 = h * 16;
        float sim[20];
        #pragma unroll
        for (int l = 0; l < 20; ++l) sim[l] = -CB[h * 20 + l];
        #pragma unroll
        for (int i = 0; i < 8; ++i) {
            const uint32_t w = qw[hh * 8 + i];
            const float qlo = bfLO(w), qhi = bfHI(w);
            const float* k0 = KN + (c0 + 2 * i) * 20;
            #pragma unroll
            for (int l = 0; l < 20; ++l)
                sim[l] = fmaf(qlo, k0[l], fmaf(qhi, k0[20 + l], sim[l]));
        }
        float mx = sim[0];
        #pragma unroll
        for (int l = 1; l < 20; ++l) mx = fmaxf(mx, sim[l]);
        float se = 0.0f;
        #pragma unroll
        for (int l = 0; l < 20; ++l) { float e = __expf(sim[l] - mx); sim[l] = e; se += e; }
        const float inv = 1.0f / se;
        #pragma unroll
        for (int i = 0; i < 8; ++i) {
            const float* v0 = VV + (c0 + 2 * i) * 20;
            float x0 = 0.0f, x1 = 0.0f;
            #pragma unroll
            for (int l = 0; l < 20; ++l) {
                x0 = fmaf(sim[l], v0[l], x0);
                x1 = fmaf(sim[l], v0[20 + l], x1);
            }
            QX[p * 65 + h * 8 + i] = pk2f(x0 * inv, x1 * inv);
        }
    }
    __syncthreads();

    {
        const int lane = t & 63, w = t >> 6;
        uint32_t* gdst = (uint32_t*)(xout + bbase + (size_t)pblk * NCH);
        #pragma unroll
        for (int j = 0; j < 4; ++j) {
            const int pp = w * 4 + j * 16 + (lane >> 4);
            const int cw = (lane & 15) * 4;
            const uint32_t* s = QX + pp * 65 + cw;
            *(uint4*)(gdst + pp * 64 + cw) = make_uint4(s[0], s[1], s[2], s[3]);
        }
    }
}

// ---------------------------------------------------------------------------
extern "C" void kernel_launch(void* const* d_in, const int* in_sizes, int n_in,
                              void* d_out, int out_size, void* d_ws, size_t ws_size,
                              hipStream_t stream)
{
    const float* img  = (const float*)d_in[0];
    const float* lang = (const float*)d_in[1];
    const float* Wq   = (const float*)d_in[2];
    const float* bq   = (const float*)d_in[3];
    const float* Wk   = (const float*)d_in[4];
    const float* bk   = (const float*)d_in[5];
    const float* Wv   = (const float*)d_in[6];
    const float* bv   = (const float*)d_in[7];
    const float* Wpw  = (const float*)d_in[8];
    const float* bpw  = (const float*)d_in[9];
    const float* Wpi  = (const float*)d_in[10];
    const float* bpi  = (const float*)d_in[11];
    const float* Wpo  = (const float*)d_in[12];
    const float* bpo  = (const float*)d_in[13];
    const float* Wg1  = (const float*)d_in[14];
    const float* bg1  = (const float*)d_in[15];
    const float* Wg2  = (const float*)d_in[16];
    const float* bg2  = (const float*)d_in[17];
    float* outp = (float*)d_out;

    const size_t N = (size_t)NB * NCH * PSP;
    const size_t needed = 3 * N * sizeof(short) + 6 * NCH * NCH * sizeof(short)
                        + (3 * 2 * 2560 + 2 * 160 + 6 * 256) * sizeof(float);
    if (ws_size < needed) return;

    short* bufA = (short*)d_ws;          // q_pre, then weight_pre
    short* bufB = bufA + N;              // x, then 'out'
    short* bufC = bufB + N;              // skip_pre
    short* wt16 = bufC + N;
    float* kbuf = (float*)(wt16 + 6 * NCH * NCH);
    float* vbuf = kbuf + 2 * 2560;
    float* knb  = vbuf + 2 * 2560;
    float* cbb  = knb + 2 * 2560;
    float* st   = cbb + 2 * 160;
    float* qs   = st;
    float* qs2  = st + 256;
    float* ss   = st + 512;
    float* ss2  = st + 768;
    float* wsu  = st + 1024;
    float* ws2  = st + 1280;

    (void)hipMemsetAsync(st, 0, 6 * 256 * sizeof(float), stream);
    kv_kernel<<<dim3(40), dim3(256), 0, stream>>>(lang, Wk, bk, Wv, bv, kbuf, vbuf);
    wprep_kernel<<<dim3(96), dim3(256), 0, stream>>>(Wq, Wpi, Wpw, Wpo, Wg1, Wg2, wt16);

    const dim3 gg(PSP / (64 * TPB), NB), gb(256);

    g12_kernel<<<gg, gb, 0, stream>>>(img, wt16, bq, bpi, bufA, bufC, qs, qs2, ss, ss2);
    knprep_kernel<<<dim3(NB), dim3(256), 0, stream>>>(qs, qs2, kbuf, knb, cbb);
    attn3_kernel<<<dim3(PSP / 64, NB), gb, 0, stream>>>(bufA, knb, cbb, vbuf, bufB);
    g3_kernel<<<gg, gb, 0, stream>>>(bufB, wt16 + 2 * NCH * NCH, bpw, bufA, wsu, ws2);
    g4_kernel<<<gg, gb, 0, stream>>>(bufC, bufA, ss, ss2, wsu, ws2,
                                     wt16 + 3 * NCH * NCH, bpo, bufB);
    g56_kernel<<<gg, gb, 0, stream>>>(bufB, wt16 + 4 * NCH * NCH, bg1,
                                      wt16 + 5 * NCH * NCH, bg2, outp);
}